// Round 1
// 449.877 us; speedup vs baseline: 1.1290x; 1.1290x over previous
//
#include <hip/hip_runtime.h>
#include <hip/hip_bf16.h>

#define T_SEQ 4096
#define HIDDEN 2560
#define NH 8
#define NKV 4
#define HD 256
#define WINDOW 1024
#define SM_SCALE 0.0625f

typedef __bf16 bf16x8 __attribute__((ext_vector_type(8)));
typedef float f32x4 __attribute__((ext_vector_type(4)));
typedef __hip_bfloat16 bf16;

#define GLOAD_LDS(g, l) \
  __builtin_amdgcn_global_load_lds((const __attribute__((address_space(1))) void*)(g), \
                                   (__attribute__((address_space(3))) void*)(l), 16, 0, 0)

// ---------- fp32 -> bf16 elementwise convert (8 elems/thread) ----------
__global__ __launch_bounds__(256) void k_f2b(
    const float* __restrict__ src, bf16* __restrict__ dst)
{
  const size_t i = (size_t)blockIdx.x * 256 + threadIdx.x;
  const float4 a = ((const float4*)src)[i * 2];
  const float4 b = ((const float4*)src)[i * 2 + 1];
  bf16 tmp[8];
  tmp[0] = __float2bfloat16(a.x); tmp[1] = __float2bfloat16(a.y);
  tmp[2] = __float2bfloat16(a.z); tmp[3] = __float2bfloat16(a.w);
  tmp[4] = __float2bfloat16(b.x); tmp[5] = __float2bfloat16(b.y);
  tmp[6] = __float2bfloat16(b.z); tmp[7] = __float2bfloat16(b.w);
  *(bf16x8*)(dst + i * 8) = *(bf16x8*)tmp;
}

// ---------- fp32 src -> bf16 dst 64x64-tile transpose: dst[c][r] = (bf16)src[r][c] ----------
__global__ __launch_bounds__(256) void k_transpose_f2b(
    const float* __restrict__ src, bf16* __restrict__ dst, int srs, int drs)
{
  __shared__ bf16 t[64 * 72];  // +8 pad breaks bank conflicts on transposed read
  const int tid = threadIdx.x;
  const int c0 = blockIdx.x * 64;
  const int r0 = blockIdx.y * 64;
  const int rr = tid >> 3;
  const int cc = (tid & 7) * 8;
#pragma unroll
  for (int p = 0; p < 2; ++p) {
    const float* sp = src + (size_t)(r0 + p * 32 + rr) * srs + c0 + cc;
    const float4 a = *(const float4*)sp;
    const float4 b = *(const float4*)(sp + 4);
    bf16* tp = &t[(p * 32 + rr) * 72 + cc];
    tp[0] = __float2bfloat16(a.x); tp[1] = __float2bfloat16(a.y);
    tp[2] = __float2bfloat16(a.z); tp[3] = __float2bfloat16(a.w);
    tp[4] = __float2bfloat16(b.x); tp[5] = __float2bfloat16(b.y);
    tp[6] = __float2bfloat16(b.z); tp[7] = __float2bfloat16(b.w);
  }
  __syncthreads();
#pragma unroll
  for (int p = 0; p < 2; ++p) {
    const int n = p * 32 + rr;
    bf16x8 v;
#pragma unroll
    for (int i = 0; i < 8; ++i) v[i] = ((const __bf16*)t)[(cc + i) * 72 + n];
    *(bf16x8*)(dst + (size_t)(c0 + n) * drs + r0 + cc) = v;
  }
}

// ---------- bf16 64x64-tile transpose (for V): dst[c][r] = src[r][c] ----------
__global__ __launch_bounds__(256) void k_transpose(
    const bf16* __restrict__ src, bf16* __restrict__ dst,
    int srs, int drs, long src_zoff, long dst_zoff)
{
  __shared__ bf16 t[64 * 72];
  src += (size_t)blockIdx.z * src_zoff;
  dst += (size_t)blockIdx.z * dst_zoff;
  const int tid = threadIdx.x;
  const int c0 = blockIdx.x * 64;
  const int r0 = blockIdx.y * 64;
  const int rr = tid >> 3;
  const int cc = (tid & 7) * 8;
#pragma unroll
  for (int p = 0; p < 2; ++p) {
    bf16x8 v = *(const bf16x8*)(src + (size_t)(r0 + p * 32 + rr) * srs + c0 + cc);
    *(bf16x8*)(&t[(p * 32 + rr) * 72 + cc]) = v;
  }
  __syncthreads();
#pragma unroll
  for (int p = 0; p < 2; ++p) {
    const int n = p * 32 + rr;
    bf16x8 v;
#pragma unroll
    for (int i = 0; i < 8; ++i) v[i] = ((const __bf16*)t)[(cc + i) * 72 + n];
    *(bf16x8*)(dst + (size_t)(c0 + n) * drs + r0 + cc) = v;
  }
}

// ---------- 256x256-tile 8-phase bf16 GEMM (m201 template): C = A[M][K] * Bt[N][K]^T ----------
// T1 XCD swizzle + T2 LDS XOR-swizzle + T3/T4 8-phase counted-vmcnt + T5 setprio.
// 8 waves (2M x 4N), per-wave output 128x64, BK=64, LDS 128 KiB double-buffered.
// Staging: B-halves staged 1 K-tile ahead, A-halves 2 K-tiles ahead -> boundary wait
// is vmcnt(4) (the 2 in-flight A-halves), never a full drain (T4).
// Swizzle involution: byte-offset bits 4..6 ^= (row&7); applied to BOTH the
// global_load_lds source (pre-swizzle) and the ds_read address (rule 21).
template <typename OutT>
__global__ __launch_bounds__(512, 2) void k_gemm8(
    const bf16* __restrict__ A, const bf16* __restrict__ Bt,
    OutT* __restrict__ C, int M, int N, int K)
{
  __shared__ bf16 As[2 * 256 * 64];
  __shared__ bf16 Bs[2 * 256 * 64];
  constexpr int BUFB = 256 * 64 * 2;  // bytes per buffer

  const int tid = threadIdx.x;
  const int wave = tid >> 6;
  const int lane = tid & 63;
  const int l16 = lane & 15;
  const int quad = lane >> 4;
  const int wm = wave >> 2;   // 0..1 -> rows wm*128..+127
  const int wn = wave & 3;    // 0..3 -> cols wn*64..+63

  // XCD-aware bijective swizzle (both launches have nwg % 8 == 0)
  int id = blockIdx.y * gridDim.x + blockIdx.x;
  const int nwg = gridDim.x * gridDim.y;
  const int chunk = nwg >> 3;
  id = (id & 7) * chunk + (id >> 3);
  const int bx = id % gridDim.x;
  const int by = id / gridDim.x;
  const int m0 = by * 256;
  const int n0 = bx * 256;

  const int NT = K >> 6;           // K-tiles of 64
  const int xorv = (l16 & 7) << 4; // T2 swizzle key for fragment reads

  // staging source bases (per-lane, pre-swizzled: col chunk = (l&7)^(l>>3))
  const bf16* srcA = A + (size_t)(m0 + wave * 16 + (lane >> 3)) * K + ((lane & 7) ^ (lane >> 3)) * 8;
  const bf16* srcB = Bt + (size_t)(n0 + wave * 16 + (lane >> 3)) * K + ((lane & 7) ^ (lane >> 3)) * 8;

  auto stage_a = [&](int buf, int h, int kt) {
    const bf16* sp = srcA + (size_t)(h * 128) * K + kt * 64;
    char* dp = (char*)As + buf * BUFB + h * 16384 + wave * 2048;  // wave-uniform; HW adds lane*16
    GLOAD_LDS(sp, dp);
    GLOAD_LDS(sp + (size_t)8 * K, dp + 1024);
  };
  auto stage_b = [&](int buf, int h, int kt) {
    const bf16* sp = srcB + (size_t)(h * 128) * K + kt * 64;
    char* dp = (char*)Bs + buf * BUFB + h * 16384 + wave * 2048;
    GLOAD_LDS(sp, dp);
    GLOAD_LDS(sp + (size_t)8 * K, dp + 1024);
  };

  bf16x8 afr[8][2];  // A row-frags 0..7 x k-slice 0..1
  bf16x8 bfr[4][2];  // B col-frags 0..3 x k-slice
  f32x4 acc[8][4] = {};

  // prologue: kt0 fully, kt1 A-halves; wait for kt0 (leave 4 loads in flight)
  stage_a(0, 0, 0); stage_a(0, 1, 0);
  stage_b(0, 0, 0); stage_b(0, 1, 0);
  stage_a(1, 0, 1); stage_a(1, 1, 1);
  asm volatile("s_waitcnt vmcnt(4)" ::: "memory");
  __builtin_amdgcn_s_barrier();

  for (int kt = 0; kt < NT; ++kt) {
    const int bsel = kt & 1;
    const char* Ab = (const char*)As + bsel * BUFB;
    const char* Bb = (const char*)Bs + bsel * BUFB;

    auto read_a = [&](int I0) {
#pragma unroll
      for (int ii = 0; ii < 4; ++ii)
#pragma unroll
        for (int s = 0; s < 2; ++s)
          afr[I0 + ii][s] = *(const bf16x8*)(
              Ab + (wm * 128 + (I0 + ii) * 16 + l16) * 128 + ((s * 64 + quad * 16) ^ xorv));
    };
    auto read_b = [&](int J0) {
#pragma unroll
      for (int jj = 0; jj < 2; ++jj)
#pragma unroll
        for (int s = 0; s < 2; ++s)
          bfr[J0 + jj][s] = *(const bf16x8*)(
              Bb + (wn * 64 + (J0 + jj) * 16 + l16) * 128 + ((s * 64 + quad * 16) ^ xorv));
    };
    auto mfma_quad = [&](int I0, int J0) {
#pragma unroll
      for (int ii = 0; ii < 4; ++ii)
#pragma unroll
        for (int jj = 0; jj < 2; ++jj)
#pragma unroll
          for (int s = 0; s < 2; ++s)
            acc[I0 + ii][J0 + jj] = __builtin_amdgcn_mfma_f32_16x16x32_bf16(
                afr[I0 + ii][s], bfr[J0 + jj][s], acc[I0 + ii][J0 + jj], 0, 0, 0);
    };

    // ---- phase 1: read a0+b0 (12 ds_read), stage Bh0(kt+1), mfma a0*b0
    read_a(0);
    read_b(0);
    if (kt + 1 < NT) stage_b(bsel ^ 1, 0, kt + 1);
    asm volatile("s_waitcnt lgkmcnt(8)" ::: "memory");
    __builtin_amdgcn_s_barrier();
    asm volatile("s_waitcnt lgkmcnt(0)" ::: "memory");
    __builtin_amdgcn_sched_barrier(0);
    __builtin_amdgcn_s_setprio(1);
    mfma_quad(0, 0);
    __builtin_amdgcn_s_setprio(0);
    __builtin_amdgcn_s_barrier();
    // ---- phase 2: read a1, stage Bh1(kt+1), mfma a1*b0
    read_a(4);
    if (kt + 1 < NT) stage_b(bsel ^ 1, 1, kt + 1);
    __builtin_amdgcn_s_barrier();
    asm volatile("s_waitcnt lgkmcnt(0)" ::: "memory");
    __builtin_amdgcn_sched_barrier(0);
    __builtin_amdgcn_s_setprio(1);
    mfma_quad(4, 0);
    __builtin_amdgcn_s_setprio(0);
    __builtin_amdgcn_s_barrier();
    // ---- phase 3: read b1, stage Ah0(kt+2) (A reads of kt done after P2), mfma a1*b1
    read_b(2);
    if (kt + 2 < NT) stage_a(bsel, 0, kt + 2);
    __builtin_amdgcn_s_barrier();
    asm volatile("s_waitcnt lgkmcnt(0)" ::: "memory");
    __builtin_amdgcn_sched_barrier(0);
    __builtin_amdgcn_s_setprio(1);
    mfma_quad(4, 2);
    __builtin_amdgcn_s_setprio(0);
    __builtin_amdgcn_s_barrier();
    // ---- phase 4: stage Ah1(kt+2), mfma a0*b1, counted boundary wait
    if (kt + 2 < NT) stage_a(bsel, 1, kt + 2);
    __builtin_amdgcn_s_barrier();
    __builtin_amdgcn_s_setprio(1);
    mfma_quad(0, 2);
    __builtin_amdgcn_s_setprio(0);
    if (kt + 2 < NT) {
      // leave the 2 A-halves of kt+2 (4 loads) in flight; everything older landed
      asm volatile("s_waitcnt vmcnt(4)" ::: "memory");
    } else if (kt + 1 < NT) {
      // tail: no A-halves were staged this iter; must drain B-halves of kt+1
      asm volatile("s_waitcnt vmcnt(0)" ::: "memory");
    }
    __builtin_amdgcn_s_barrier();
  }

  // epilogue: C/D layout col = lane&15, row = quad*4 + reg
#pragma unroll
  for (int i = 0; i < 8; ++i)
#pragma unroll
    for (int j = 0; j < 4; ++j) {
      const int col = n0 + wn * 64 + j * 16 + l16;
#pragma unroll
      for (int r = 0; r < 4; ++r) {
        const int row = m0 + wm * 128 + i * 16 + quad * 4 + r;
        if constexpr (__is_same(OutT, float))
          C[(size_t)row * N + col] = acc[i][j][r];
        else
          C[(size_t)row * N + col] = __float2bfloat16(acc[i][j][r]);
      }
    }
}

// ---------- RMSNorm (fp32) + RoPE for q (slots 0..7) and k (slots 8..11) ----------
__global__ __launch_bounds__(64) void k_norm_rope(
    const bf16* __restrict__ qkv, const int* __restrict__ positions,
    const float* __restrict__ qw, const float* __restrict__ kw,
    bf16* __restrict__ q_r, bf16* __restrict__ k_r)
{
  const int t = blockIdx.x;
  const int slot = blockIdx.y;
  const int lane = threadIdx.x;
  const bf16* base = qkv + (size_t)t * 4096 + slot * 256;
  float x[4];
#pragma unroll
  for (int i = 0; i < 4; ++i) x[i] = __bfloat162float(base[lane + 64 * i]);
  float ss = x[0] * x[0] + x[1] * x[1] + x[2] * x[2] + x[3] * x[3];
#pragma unroll
  for (int off = 1; off < 64; off <<= 1) ss += __shfl_xor(ss, off, 64);
  const float rn = rsqrtf(ss * (1.0f / 256.0f) + 1e-6f);
  const float* w = (slot < 8) ? qw : kw;
  float nv[4];
#pragma unroll
  for (int i = 0; i < 4; ++i)
    nv[i] = x[i] * rn * (1.0f + w[lane + 64 * i]);
  // RoPE: dim pairs (d, d+128); thread's dims: lane, lane+64, lane+128, lane+192
  const float p = (float)positions[t];
  const float C_LOG2_10K_128 = 13.287712379549449f / 128.0f;
  const float f0 = p * exp2f(-(float)lane * C_LOG2_10K_128);
  const float f1 = p * exp2f(-(float)(lane + 64) * C_LOG2_10K_128);
  const float c0 = cosf(f0), s0 = sinf(f0);
  const float c1 = cosf(f1), s1 = sinf(f1);
  const float o0 = nv[0] * c0 - nv[2] * s0;
  const float o2 = nv[2] * c0 + nv[0] * s0;
  const float o1 = nv[1] * c1 - nv[3] * s1;
  const float o3 = nv[3] * c1 + nv[1] * s1;
  bf16* dst = (slot < 8) ? (q_r + ((size_t)slot * T_SEQ + t) * 256)
                         : (k_r + ((size_t)(slot - 8) * T_SEQ + t) * 256);
  dst[lane]       = __float2bfloat16(o0);
  dst[lane + 64]  = __float2bfloat16(o1);
  dst[lane + 128] = __float2bfloat16(o2);
  dst[lane + 192] = __float2bfloat16(o3);
}

// ---------- flash attention, sliding window, GQA ----------
// q_r [8][T][256], k_r [4][T][256], vt [4][256][T], attn [T][2048]
__global__ __launch_bounds__(256) void k_attn(
    const bf16* __restrict__ q_r, const bf16* __restrict__ k_r,
    const bf16* __restrict__ vt, bf16* __restrict__ attn)
{
  __shared__ bf16 Ks[32 * 256];    // [key][d]
  __shared__ bf16 Vts[256 * 32];   // [d][key]
  __shared__ bf16 Ps[4 * 16 * 32]; // per-wave P: [16 q][32 key]
  const int tid = threadIdx.x;
  const int wave = tid >> 6;
  const int lane = tid & 63;
  const int l16 = lane & 15;
  const int quad = lane >> 4;
  const int q0 = blockIdx.x * 64;
  const int h = blockIdx.y;
  const int kh = h >> 1;

  // Q A-fragments stay in registers: A[m=lane&15][k=quad*8+j], 8 k-steps of 32
  bf16x8 qf[8];
  {
    const bf16* qb = q_r + ((size_t)h * T_SEQ + q0 + wave * 16 + l16) * HD + quad * 8;
#pragma unroll
    for (int s = 0; s < 8; ++s) qf[s] = *(const bf16x8*)(qb + s * 32);
  }
  f32x4 O[16] = {};
  float mrow[4], lrow[4];
#pragma unroll
  for (int r = 0; r < 4; ++r) { mrow[r] = -1e30f; lrow[r] = 0.f; }

  const int jstart = ((q0 > 1023) ? (q0 - 1023) : 0) & ~31;
  const int jlast = q0 + 32;
  for (int j0 = jstart; j0 <= jlast; j0 += 32) {
    __syncthreads();  // prior tile's LDS reads drained before restage
    {
      const bf16* kg = k_r + ((size_t)kh * T_SEQ + j0 + (tid >> 5)) * HD + (tid & 31) * 8;
      const bf16* vg = vt + ((size_t)kh * HD + (tid >> 2)) * T_SEQ + j0 + (tid & 3) * 8;
      char* kl = (char*)Ks + wave * 1024;
      char* vl = (char*)Vts + wave * 1024;
#pragma unroll
      for (int p = 0; p < 4; ++p) {
        GLOAD_LDS(kg + (size_t)p * 8 * HD, kl + p * 4096);
        GLOAD_LDS(vg + (size_t)p * 64 * T_SEQ, vl + p * 4096);
      }
    }
    __syncthreads();  // staged data visible (barrier drains vmcnt)

    // S = Q K^T  (16 q x 32 keys per wave)
    f32x4 sa0 = {}, sa1 = {};
#pragma unroll
    for (int s = 0; s < 8; ++s) {
      bf16x8 kf0 = *(const bf16x8*)(Ks + l16 * HD + s * 32 + quad * 8);
      bf16x8 kf1 = *(const bf16x8*)(Ks + (16 + l16) * HD + s * 32 + quad * 8);
      sa0 = __builtin_amdgcn_mfma_f32_16x16x32_bf16(qf[s], kf0, sa0, 0, 0, 0);
      sa1 = __builtin_amdgcn_mfma_f32_16x16x32_bf16(qf[s], kf1, sa1, 0, 0, 0);
    }
    // online softmax per row (row = quad*4 + r); p zeroed explicitly for masked keys
#pragma unroll
    for (int r = 0; r < 4; ++r) {
      const int i = q0 + wave * 16 + quad * 4 + r;
      const int ja = j0 + l16;
      const int jb = ja + 16;
      const bool va = (ja <= i) && (i - ja < WINDOW);
      const bool vb = (jb <= i) && (i - jb < WINDOW);
      const float s0 = va ? sa0[r] * SM_SCALE : -1e30f;
      const float s1 = vb ? sa1[r] * SM_SCALE : -1e30f;
      float mx = fmaxf(s0, s1);
#pragma unroll
      for (int off = 1; off < 16; off <<= 1) mx = fmaxf(mx, __shfl_xor(mx, off, 64));
      const float mnew = fmaxf(mrow[r], mx);
      const float alpha = __expf(mrow[r] - mnew);
      const float p0 = va ? __expf(s0 - mnew) : 0.0f;
      const float p1 = vb ? __expf(s1 - mnew) : 0.0f;
      float rs = p0 + p1;
#pragma unroll
      for (int off = 1; off < 16; off <<= 1) rs += __shfl_xor(rs, off, 64);
      lrow[r] = lrow[r] * alpha + rs;
      mrow[r] = mnew;
#pragma unroll
      for (int n = 0; n < 16; ++n) O[n][r] *= alpha;
      Ps[wave * 512 + (quad * 4 + r) * 32 + l16]      = __float2bfloat16(p0);
      Ps[wave * 512 + (quad * 4 + r) * 32 + 16 + l16] = __float2bfloat16(p1);
    }
    // C-layout -> A-layout round trip through per-wave LDS (wave-internal only)
    asm volatile("s_waitcnt lgkmcnt(0)" ::: "memory");
    bf16x8 pf = *(const bf16x8*)(Ps + wave * 512 + l16 * 32 + quad * 8);
#pragma unroll
    for (int n = 0; n < 16; ++n) {
      bf16x8 vf = *(const bf16x8*)(Vts + (n * 16 + l16) * 32 + quad * 8);
      O[n] = __builtin_amdgcn_mfma_f32_16x16x32_bf16(pf, vf, O[n], 0, 0, 0);
    }
  }
  // epilogue: O /= l, write [T][H*D]
#pragma unroll
  for (int r = 0; r < 4; ++r) {
    const float inv = 1.0f / lrow[r];
    const size_t row = q0 + wave * 16 + quad * 4 + r;
#pragma unroll
    for (int n = 0; n < 16; ++n)
      attn[row * (NH * HD) + h * HD + n * 16 + l16] = __float2bfloat16(O[n][r] * inv);
  }
}

extern "C" void kernel_launch(void* const* d_in, const int* in_sizes, int n_in,
                              void* d_out, int out_size, void* d_ws, size_t ws_size,
                              hipStream_t stream)
{
  const float* x  = (const float*)d_in[0];
  const int* pos  = (const int*)d_in[1];
  const float* Wq = (const float*)d_in[2];
  const float* Wk = (const float*)d_in[3];
  const float* Wv = (const float*)d_in[4];
  const float* Wo = (const float*)d_in[5];
  const float* qw = (const float*)d_in[6];
  const float* kw = (const float*)d_in[7];
  float* out = (float*)d_out;   // reference output dtype is FP32

  char* ws = (char*)d_ws;
  size_t off = 0;
  bf16* Wqkv_t = (bf16*)(ws + off); off += (size_t)4096 * 2560 * 2;  // dead after GEMM1; reused as attn_b
  bf16* Wo_t   = (bf16*)(ws + off); off += (size_t)2560 * 2048 * 2;
  bf16* qkv_b  = (bf16*)(ws + off); off += (size_t)4096 * 4096 * 2;
  bf16* q_r    = (bf16*)(ws + off); off += (size_t)8 * 4096 * 256 * 2;
  bf16* k_r    = (bf16*)(ws + off); off += (size_t)4 * 4096 * 256 * 2;
  bf16* v_t    = (bf16*)(ws + off); off += (size_t)4 * 256 * 4096 * 2;
  bf16* attn_b = Wqkv_t;
  // x_bf16 (21 MB) aliases q_r (16.8 MB) + head of k_r: x_b dies at GEMM1,
  // q_r/k_r are written only after GEMM1 completes.
  bf16* x_b = q_r;
  if (ws_size < off) return;  // insufficient workspace -> fail loudly

  // fp32 -> bf16 conversions: x elementwise, weights fused into B^T transposes
  k_f2b<<<dim3((4096 * 2560) / (256 * 8)), 256, 0, stream>>>(x, x_b);
  k_transpose_f2b<<<dim3(32, 40), 256, 0, stream>>>(Wq, Wqkv_t, 2048, 2560);
  k_transpose_f2b<<<dim3(16, 40), 256, 0, stream>>>(Wk, Wqkv_t + (size_t)2048 * 2560, 1024, 2560);
  k_transpose_f2b<<<dim3(16, 40), 256, 0, stream>>>(Wv, Wqkv_t + (size_t)3072 * 2560, 1024, 2560);
  k_transpose_f2b<<<dim3(40, 32), 256, 0, stream>>>(Wo, Wo_t, 2560, 2048);
  // fused QKV projection: [4096,2560] x [2560,4096] -> [4096,4096] (bf16 out), 256 blocks
  k_gemm8<bf16><<<dim3(16, 16), 512, 0, stream>>>(x_b, Wqkv_t, qkv_b, 4096, 4096, 2560);
  // RMSNorm + RoPE for q,k (overwrites x_b region -- x_b is dead now)
  k_norm_rope<<<dim3(4096, 12), 64, 0, stream>>>(qkv_b, pos, qw, kw, q_r, k_r);
  // V transpose: qkv_b[t][3072+kh*256+d] -> v_t[kh][d][t]
  k_transpose<<<dim3(4, 64, 4), 256, 0, stream>>>(qkv_b + 3072, v_t, 4096, 4096, 256, (long)256 * 4096);
  // flash attention
  k_attn<<<dim3(64, 8), 256, 0, stream>>>(q_r, k_r, v_t, attn_b);
  // output projection: [4096,2048] x [2048,2560] -> out (FP32 out), 160 blocks
  k_gemm8<float><<<dim3(10, 16), 512, 0, stream>>>(attn_b, Wo_t, out, 4096, 2560, 2048);
}

// Round 2
// 416.545 us; speedup vs baseline: 1.2193x; 1.0800x over previous
//
#include <hip/hip_runtime.h>
#include <hip/hip_bf16.h>

#define T_SEQ 4096
#define HIDDEN 2560
#define NH 8
#define NKV 4
#define HD 256
#define WINDOW 1024
#define SM_SCALE 0.0625f

typedef __bf16 bf16x8 __attribute__((ext_vector_type(8)));
typedef float f32x4 __attribute__((ext_vector_type(4)));
typedef __hip_bfloat16 bf16;

#define GLOAD_LDS(g, l) \
  __builtin_amdgcn_global_load_lds((const __attribute__((address_space(1))) void*)(g), \
                                   (__attribute__((address_space(3))) void*)(l), 16, 0, 0)

// ---------- fp32 -> bf16 elementwise convert (8 elems/thread) ----------
__global__ __launch_bounds__(256) void k_f2b(
    const float* __restrict__ src, bf16* __restrict__ dst)
{
  const size_t i = (size_t)blockIdx.x * 256 + threadIdx.x;
  const float4 a = ((const float4*)src)[i * 2];
  const float4 b = ((const float4*)src)[i * 2 + 1];
  bf16 tmp[8];
  tmp[0] = __float2bfloat16(a.x); tmp[1] = __float2bfloat16(a.y);
  tmp[2] = __float2bfloat16(a.z); tmp[3] = __float2bfloat16(a.w);
  tmp[4] = __float2bfloat16(b.x); tmp[5] = __float2bfloat16(b.y);
  tmp[6] = __float2bfloat16(b.z); tmp[7] = __float2bfloat16(b.w);
  *(bf16x8*)(dst + i * 8) = *(bf16x8*)tmp;
}

// ---------- fp32 src -> bf16 dst 64x64-tile transpose: dst[c][r] = (bf16)src[r][c] ----------
__global__ __launch_bounds__(256) void k_transpose_f2b(
    const float* __restrict__ src, bf16* __restrict__ dst, int srs, int drs)
{
  __shared__ bf16 t[64 * 72];  // +8 pad breaks bank conflicts on transposed read
  const int tid = threadIdx.x;
  const int c0 = blockIdx.x * 64;
  const int r0 = blockIdx.y * 64;
  const int rr = tid >> 3;
  const int cc = (tid & 7) * 8;
#pragma unroll
  for (int p = 0; p < 2; ++p) {
    const float* sp = src + (size_t)(r0 + p * 32 + rr) * srs + c0 + cc;
    const float4 a = *(const float4*)sp;
    const float4 b = *(const float4*)(sp + 4);
    bf16* tp = &t[(p * 32 + rr) * 72 + cc];
    tp[0] = __float2bfloat16(a.x); tp[1] = __float2bfloat16(a.y);
    tp[2] = __float2bfloat16(a.z); tp[3] = __float2bfloat16(a.w);
    tp[4] = __float2bfloat16(b.x); tp[5] = __float2bfloat16(b.y);
    tp[6] = __float2bfloat16(b.z); tp[7] = __float2bfloat16(b.w);
  }
  __syncthreads();
#pragma unroll
  for (int p = 0; p < 2; ++p) {
    const int n = p * 32 + rr;
    bf16x8 v;
#pragma unroll
    for (int i = 0; i < 8; ++i) v[i] = ((const __bf16*)t)[(cc + i) * 72 + n];
    *(bf16x8*)(dst + (size_t)(c0 + n) * drs + r0 + cc) = v;
  }
}

// ---------- bf16 64x64-tile transpose (for V): dst[c][r] = src[r][c] ----------
__global__ __launch_bounds__(256) void k_transpose(
    const bf16* __restrict__ src, bf16* __restrict__ dst,
    int srs, int drs, long src_zoff, long dst_zoff)
{
  __shared__ bf16 t[64 * 72];
  src += (size_t)blockIdx.z * src_zoff;
  dst += (size_t)blockIdx.z * dst_zoff;
  const int tid = threadIdx.x;
  const int c0 = blockIdx.x * 64;
  const int r0 = blockIdx.y * 64;
  const int rr = tid >> 3;
  const int cc = (tid & 7) * 8;
#pragma unroll
  for (int p = 0; p < 2; ++p) {
    bf16x8 v = *(const bf16x8*)(src + (size_t)(r0 + p * 32 + rr) * srs + c0 + cc);
    *(bf16x8*)(&t[(p * 32 + rr) * 72 + cc]) = v;
  }
  __syncthreads();
#pragma unroll
  for (int p = 0; p < 2; ++p) {
    const int n = p * 32 + rr;
    bf16x8 v;
#pragma unroll
    for (int i = 0; i < 8; ++i) v[i] = ((const __bf16*)t)[(cc + i) * 72 + n];
    *(bf16x8*)(dst + (size_t)(c0 + n) * drs + r0 + cc) = v;
  }
}

// ---------- 256x256-tile 8-phase bf16 GEMM (m201 template): C = A[M][K] * Bt[N][K]^T ----------
template <typename OutT>
__global__ __launch_bounds__(512, 2) void k_gemm8(
    const bf16* __restrict__ A, const bf16* __restrict__ Bt,
    OutT* __restrict__ C, int M, int N, int K)
{
  __shared__ bf16 As[2 * 256 * 64];
  __shared__ bf16 Bs[2 * 256 * 64];
  constexpr int BUFB = 256 * 64 * 2;  // bytes per buffer

  const int tid = threadIdx.x;
  const int wave = tid >> 6;
  const int lane = tid & 63;
  const int l16 = lane & 15;
  const int quad = lane >> 4;
  const int wm = wave >> 2;   // 0..1 -> rows wm*128..+127
  const int wn = wave & 3;    // 0..3 -> cols wn*64..+63

  // XCD-aware bijective swizzle (both launches have nwg % 8 == 0)
  int id = blockIdx.y * gridDim.x + blockIdx.x;
  const int nwg = gridDim.x * gridDim.y;
  const int chunk = nwg >> 3;
  id = (id & 7) * chunk + (id >> 3);
  const int bx = id % gridDim.x;
  const int by = id / gridDim.x;
  const int m0 = by * 256;
  const int n0 = bx * 256;

  const int NT = K >> 6;           // K-tiles of 64
  const int xorv = (l16 & 7) << 4; // T2 swizzle key for fragment reads

  // staging source bases (per-lane, pre-swizzled: col chunk = (l&7)^(l>>3))
  const bf16* srcA = A + (size_t)(m0 + wave * 16 + (lane >> 3)) * K + ((lane & 7) ^ (lane >> 3)) * 8;
  const bf16* srcB = Bt + (size_t)(n0 + wave * 16 + (lane >> 3)) * K + ((lane & 7) ^ (lane >> 3)) * 8;

  auto stage_a = [&](int buf, int h, int kt) {
    const bf16* sp = srcA + (size_t)(h * 128) * K + kt * 64;
    char* dp = (char*)As + buf * BUFB + h * 16384 + wave * 2048;  // wave-uniform; HW adds lane*16
    GLOAD_LDS(sp, dp);
    GLOAD_LDS(sp + (size_t)8 * K, dp + 1024);
  };
  auto stage_b = [&](int buf, int h, int kt) {
    const bf16* sp = srcB + (size_t)(h * 128) * K + kt * 64;
    char* dp = (char*)Bs + buf * BUFB + h * 16384 + wave * 2048;
    GLOAD_LDS(sp, dp);
    GLOAD_LDS(sp + (size_t)8 * K, dp + 1024);
  };

  bf16x8 afr[8][2];  // A row-frags 0..7 x k-slice 0..1
  bf16x8 bfr[4][2];  // B col-frags 0..3 x k-slice
  f32x4 acc[8][4] = {};

  // prologue: kt0 fully, kt1 A-halves; wait for kt0 (leave 4 loads in flight)
  stage_a(0, 0, 0); stage_a(0, 1, 0);
  stage_b(0, 0, 0); stage_b(0, 1, 0);
  stage_a(1, 0, 1); stage_a(1, 1, 1);
  asm volatile("s_waitcnt vmcnt(4)" ::: "memory");
  __builtin_amdgcn_s_barrier();

  for (int kt = 0; kt < NT; ++kt) {
    const int bsel = kt & 1;
    const char* Ab = (const char*)As + bsel * BUFB;
    const char* Bb = (const char*)Bs + bsel * BUFB;

    auto read_a = [&](int I0) {
#pragma unroll
      for (int ii = 0; ii < 4; ++ii)
#pragma unroll
        for (int s = 0; s < 2; ++s)
          afr[I0 + ii][s] = *(const bf16x8*)(
              Ab + (wm * 128 + (I0 + ii) * 16 + l16) * 128 + ((s * 64 + quad * 16) ^ xorv));
    };
    auto read_b = [&](int J0) {
#pragma unroll
      for (int jj = 0; jj < 2; ++jj)
#pragma unroll
        for (int s = 0; s < 2; ++s)
          bfr[J0 + jj][s] = *(const bf16x8*)(
              Bb + (wn * 64 + (J0 + jj) * 16 + l16) * 128 + ((s * 64 + quad * 16) ^ xorv));
    };
    auto mfma_quad = [&](int I0, int J0) {
#pragma unroll
      for (int ii = 0; ii < 4; ++ii)
#pragma unroll
        for (int jj = 0; jj < 2; ++jj)
#pragma unroll
          for (int s = 0; s < 2; ++s)
            acc[I0 + ii][J0 + jj] = __builtin_amdgcn_mfma_f32_16x16x32_bf16(
                afr[I0 + ii][s], bfr[J0 + jj][s], acc[I0 + ii][J0 + jj], 0, 0, 0);
    };

    // ---- phase 1: read a0+b0 (12 ds_read), stage Bh0(kt+1), mfma a0*b0
    read_a(0);
    read_b(0);
    if (kt + 1 < NT) stage_b(bsel ^ 1, 0, kt + 1);
    asm volatile("s_waitcnt lgkmcnt(8)" ::: "memory");
    __builtin_amdgcn_s_barrier();
    asm volatile("s_waitcnt lgkmcnt(0)" ::: "memory");
    __builtin_amdgcn_sched_barrier(0);
    __builtin_amdgcn_s_setprio(1);
    mfma_quad(0, 0);
    __builtin_amdgcn_s_setprio(0);
    __builtin_amdgcn_s_barrier();
    // ---- phase 2: read a1, stage Bh1(kt+1), mfma a1*b0
    read_a(4);
    if (kt + 1 < NT) stage_b(bsel ^ 1, 1, kt + 1);
    __builtin_amdgcn_s_barrier();
    asm volatile("s_waitcnt lgkmcnt(0)" ::: "memory");
    __builtin_amdgcn_sched_barrier(0);
    __builtin_amdgcn_s_setprio(1);
    mfma_quad(4, 0);
    __builtin_amdgcn_s_setprio(0);
    __builtin_amdgcn_s_barrier();
    // ---- phase 3: read b1, stage Ah0(kt+2) (A reads of kt done after P2), mfma a1*b1
    read_b(2);
    if (kt + 2 < NT) stage_a(bsel, 0, kt + 2);
    __builtin_amdgcn_s_barrier();
    asm volatile("s_waitcnt lgkmcnt(0)" ::: "memory");
    __builtin_amdgcn_sched_barrier(0);
    __builtin_amdgcn_s_setprio(1);
    mfma_quad(4, 2);
    __builtin_amdgcn_s_setprio(0);
    __builtin_amdgcn_s_barrier();
    // ---- phase 4: stage Ah1(kt+2), mfma a0*b1, counted boundary wait
    if (kt + 2 < NT) stage_a(bsel, 1, kt + 2);
    __builtin_amdgcn_s_barrier();
    __builtin_amdgcn_s_setprio(1);
    mfma_quad(0, 2);
    __builtin_amdgcn_s_setprio(0);
    if (kt + 2 < NT) {
      asm volatile("s_waitcnt vmcnt(4)" ::: "memory");
    } else if (kt + 1 < NT) {
      asm volatile("s_waitcnt vmcnt(0)" ::: "memory");
    }
    __builtin_amdgcn_s_barrier();
  }

  // epilogue: C/D layout col = lane&15, row = quad*4 + reg
#pragma unroll
  for (int i = 0; i < 8; ++i)
#pragma unroll
    for (int j = 0; j < 4; ++j) {
      const int col = n0 + wn * 64 + j * 16 + l16;
#pragma unroll
      for (int r = 0; r < 4; ++r) {
        const int row = m0 + wm * 128 + i * 16 + quad * 4 + r;
        if constexpr (__is_same(OutT, float))
          C[(size_t)row * N + col] = acc[i][j][r];
        else
          C[(size_t)row * N + col] = __float2bfloat16(acc[i][j][r]);
      }
    }
}

// ---------- RMSNorm (fp32) + RoPE for q (slots 0..7) and k (slots 8..11) ----------
__global__ __launch_bounds__(64) void k_norm_rope(
    const bf16* __restrict__ qkv, const int* __restrict__ positions,
    const float* __restrict__ qw, const float* __restrict__ kw,
    bf16* __restrict__ q_r, bf16* __restrict__ k_r)
{
  const int t = blockIdx.x;
  const int slot = blockIdx.y;
  const int lane = threadIdx.x;
  const bf16* base = qkv + (size_t)t * 4096 + slot * 256;
  float x[4];
#pragma unroll
  for (int i = 0; i < 4; ++i) x[i] = __bfloat162float(base[lane + 64 * i]);
  float ss = x[0] * x[0] + x[1] * x[1] + x[2] * x[2] + x[3] * x[3];
#pragma unroll
  for (int off = 1; off < 64; off <<= 1) ss += __shfl_xor(ss, off, 64);
  const float rn = rsqrtf(ss * (1.0f / 256.0f) + 1e-6f);
  const float* w = (slot < 8) ? qw : kw;
  float nv[4];
#pragma unroll
  for (int i = 0; i < 4; ++i)
    nv[i] = x[i] * rn * (1.0f + w[lane + 64 * i]);
  const float p = (float)positions[t];
  const float C_LOG2_10K_128 = 13.287712379549449f / 128.0f;
  const float f0 = p * exp2f(-(float)lane * C_LOG2_10K_128);
  const float f1 = p * exp2f(-(float)(lane + 64) * C_LOG2_10K_128);
  const float c0 = cosf(f0), s0 = sinf(f0);
  const float c1 = cosf(f1), s1 = sinf(f1);
  const float o0 = nv[0] * c0 - nv[2] * s0;
  const float o2 = nv[2] * c0 + nv[0] * s0;
  const float o1 = nv[1] * c1 - nv[3] * s1;
  const float o3 = nv[3] * c1 + nv[1] * s1;
  bf16* dst = (slot < 8) ? (q_r + ((size_t)slot * T_SEQ + t) * 256)
                         : (k_r + ((size_t)(slot - 8) * T_SEQ + t) * 256);
  dst[lane]       = __float2bfloat16(o0);
  dst[lane + 64]  = __float2bfloat16(o1);
  dst[lane + 128] = __float2bfloat16(o2);
  dst[lane + 192] = __float2bfloat16(o3);
}

// ---------- flash attention, sliding window, GQA ----------
// q_r [8][T][256], k_r [4][T][256], vt [4][256][T], attn [T][2048]
// T1: per-head XCD swizzle (64 q-tiles of one head per XCD -> K/V L2-resident).
// T2: XOR-swizzled K ([32][256], chunk^=row&7), V ([256][32], chunk^=row&3),
//     P ([16][32] per wave, chunk^=row>>2); both-sides (pre-swizzled gload src).
// T3/T4: double-buffered K/V staging with counted vmcnt(8), raw s_barrier.
// T13: defer-max (THR=8) skips the O-rescale on most tiles.
__global__ __launch_bounds__(256) void k_attn(
    const bf16* __restrict__ q_r, const bf16* __restrict__ k_r,
    const bf16* __restrict__ vt, bf16* __restrict__ attn)
{
  __shared__ bf16 Ks[2][32 * 256];    // [key][d], d-chunk xor (row&7)
  __shared__ bf16 Vts[2][256 * 32];   // [d][key], key-chunk xor (row&3)
  __shared__ bf16 Ps[4 * 16 * 32];    // per-wave P: [16 q][32 key], chunk xor (row>>2)
  const int tid = threadIdx.x;
  const int wave = tid >> 6;
  const int lane = tid & 63;
  const int l16 = lane & 15;
  const int quad = lane >> 4;
  // XCD swizzle: dispatch id B (round-robins XCDs) -> orig id (B&7)*64 + B>>3,
  // so XCD k runs all 64 q-tiles of head k (its K+V = 4 MB = one XCD L2).
  const int bid = blockIdx.y * gridDim.x + blockIdx.x;   // 512 blocks
  const int orig = (bid & 7) * 64 + (bid >> 3);
  const int q0 = (orig & 63) * 64;
  const int h = orig >> 6;
  const int kh = h >> 1;

  // Q A-fragments stay in registers: A[m=lane&15][k=quad*8+j], 8 k-steps of 32
  bf16x8 qf[8];
  {
    const bf16* qb = q_r + ((size_t)h * T_SEQ + q0 + wave * 16 + l16) * HD + quad * 8;
#pragma unroll
    for (int s = 0; s < 8; ++s) qf[s] = *(const bf16x8*)(qb + s * 32);
  }
  f32x4 O[16] = {};
  float mrow[4], lrow[4];
#pragma unroll
  for (int r = 0; r < 4; ++r) { mrow[r] = -1e30f; lrow[r] = 0.f; }

  // staging source bases, cols pre-swizzled to match linear LDS dest (rule 21):
  // K lane writes LDS row (tid>>5), chunk (tid&31) -> src col-chunk (tid&31)^(row&7)
  // V lane writes LDS row d=(tid>>2), chunk (tid&3) -> src key-chunk (tid&3)^(d&3)
  const bf16* kgb = k_r + ((size_t)kh * T_SEQ + (tid >> 5)) * HD + (((tid & 31) ^ (tid >> 5)) * 8);
  const bf16* vgb = vt + ((size_t)kh * HD + (tid >> 2)) * T_SEQ + (((tid & 3) ^ ((tid >> 2) & 3)) * 8);

  auto stage = [&](int buf, int j) {
    const bf16* kg = kgb + (size_t)j * HD;
    const bf16* vg = vgb + j;
    char* kl = (char*)Ks[buf] + wave * 1024;
    char* vl = (char*)Vts[buf] + wave * 1024;
#pragma unroll
    for (int p = 0; p < 4; ++p) {
      GLOAD_LDS(kg + (size_t)p * 8 * HD, kl + p * 4096);
      GLOAD_LDS(vg + (size_t)p * 64 * T_SEQ, vl + p * 4096);
    }
  };

  const int jstart = ((q0 > 1023) ? (q0 - 1023) : 0) & ~31;
  const int jlast = q0 + 32;
  const int k7 = l16 & 7;   // K read xor key (rows l16 and 16+l16 share row&7)
  const int v3 = l16 & 3;   // V read xor key
  bf16* Pw = Ps + wave * 512;

  stage(0, jstart);
  int it = 0;
  for (int j0 = jstart; j0 <= jlast; j0 += 32, ++it) {
    const int cur = it & 1;
    if (j0 + 32 <= jlast) {
      stage(cur ^ 1, j0 + 32);                        // issue next tile early
      asm volatile("s_waitcnt vmcnt(8)" ::: "memory"); // cur landed; next in flight
    } else {
      asm volatile("s_waitcnt vmcnt(0)" ::: "memory");
    }
    __builtin_amdgcn_s_barrier();

    const bf16* Kc = Ks[cur];
    const bf16* Vc = Vts[cur];

    // S = Q K^T  (16 q x 32 keys per wave)
    f32x4 sa0 = {}, sa1 = {};
#pragma unroll
    for (int s = 0; s < 8; ++s) {
      const int ch = ((s * 4 + quad) ^ k7) * 8;
      bf16x8 kf0 = *(const bf16x8*)(Kc + l16 * HD + ch);
      bf16x8 kf1 = *(const bf16x8*)(Kc + (16 + l16) * HD + ch);
      sa0 = __builtin_amdgcn_mfma_f32_16x16x32_bf16(qf[s], kf0, sa0, 0, 0, 0);
      sa1 = __builtin_amdgcn_mfma_f32_16x16x32_bf16(qf[s], kf1, sa1, 0, 0, 0);
    }
    // masks + per-row tile max (rows = quad*4 + r)
    float sm0[4], sm1[4], mx4[4];
    bool va4[4], vb4[4];
    bool ok = true;
#pragma unroll
    for (int r = 0; r < 4; ++r) {
      const int i = q0 + wave * 16 + quad * 4 + r;
      const int ja = j0 + l16;
      const int jb = ja + 16;
      va4[r] = (ja <= i) && (i - ja < WINDOW);
      vb4[r] = (jb <= i) && (i - jb < WINDOW);
      sm0[r] = va4[r] ? sa0[r] * SM_SCALE : -1e30f;
      sm1[r] = vb4[r] ? sa1[r] * SM_SCALE : -1e30f;
      float mx = fmaxf(sm0[r], sm1[r]);
#pragma unroll
      for (int off = 1; off < 16; off <<= 1) mx = fmaxf(mx, __shfl_xor(mx, off, 64));
      mx4[r] = mx;
      ok = ok && (mx <= mrow[r] + 8.0f);
    }
    // T13 defer-max: rescale only when some row's max grew past THR=8
    if (!__all(ok)) {
#pragma unroll
      for (int r = 0; r < 4; ++r) {
        const float mnew = fmaxf(mrow[r], mx4[r]);
        const float alpha = __expf(mrow[r] - mnew);
        lrow[r] *= alpha;
#pragma unroll
        for (int n = 0; n < 16; ++n) O[n][r] *= alpha;
        mrow[r] = mnew;
      }
    }
#pragma unroll
    for (int r = 0; r < 4; ++r) {
      const float p0 = va4[r] ? __expf(sm0[r] - mrow[r]) : 0.0f;  // bounded by e^8
      const float p1 = vb4[r] ? __expf(sm1[r] - mrow[r]) : 0.0f;
      float rs = p0 + p1;
#pragma unroll
      for (int off = 1; off < 16; off <<= 1) rs += __shfl_xor(rs, off, 64);
      lrow[r] += rs;
      const int prow = quad * 4 + r;
      Pw[prow * 32 + (((l16 >> 3) ^ quad) * 8) + (l16 & 7)]       = __float2bfloat16(p0);
      Pw[prow * 32 + ((((l16 >> 3) + 2) ^ quad) * 8) + (l16 & 7)] = __float2bfloat16(p1);
    }
    // C-layout -> A-layout round trip through per-wave LDS (wave-internal only)
    asm volatile("s_waitcnt lgkmcnt(0)" ::: "memory");
    __builtin_amdgcn_sched_barrier(0);
    bf16x8 pf = *(const bf16x8*)(Pw + l16 * 32 + ((quad ^ (l16 >> 2)) * 8));
#pragma unroll
    for (int n = 0; n < 16; ++n) {
      bf16x8 vf = *(const bf16x8*)(Vc + (n * 16 + l16) * 32 + ((quad ^ v3) * 8));
      O[n] = __builtin_amdgcn_mfma_f32_16x16x32_bf16(pf, vf, O[n], 0, 0, 0);
    }
    __builtin_amdgcn_s_barrier();   // reads of cur done; next iter may restage it
  }
  // epilogue: O /= l, write [T][H*D]
#pragma unroll
  for (int r = 0; r < 4; ++r) {
    const float inv = 1.0f / lrow[r];
    const size_t row = q0 + wave * 16 + quad * 4 + r;
#pragma unroll
    for (int n = 0; n < 16; ++n)
      attn[row * (NH * HD) + h * HD + n * 16 + l16] = __float2bfloat16(O[n][r] * inv);
  }
}

extern "C" void kernel_launch(void* const* d_in, const int* in_sizes, int n_in,
                              void* d_out, int out_size, void* d_ws, size_t ws_size,
                              hipStream_t stream)
{
  const float* x  = (const float*)d_in[0];
  const int* pos  = (const int*)d_in[1];
  const float* Wq = (const float*)d_in[2];
  const float* Wk = (const float*)d_in[3];
  const float* Wv = (const float*)d_in[4];
  const float* Wo = (const float*)d_in[5];
  const float* qw = (const float*)d_in[6];
  const float* kw = (const float*)d_in[7];
  float* out = (float*)d_out;   // reference output dtype is FP32

  char* ws = (char*)d_ws;
  size_t off = 0;
  bf16* Wqkv_t = (bf16*)(ws + off); off += (size_t)4096 * 2560 * 2;  // dead after GEMM1; reused as attn_b
  bf16* Wo_t   = (bf16*)(ws + off); off += (size_t)2560 * 2048 * 2;
  bf16* qkv_b  = (bf16*)(ws + off); off += (size_t)4096 * 4096 * 2;
  bf16* q_r    = (bf16*)(ws + off); off += (size_t)8 * 4096 * 256 * 2;
  bf16* k_r    = (bf16*)(ws + off); off += (size_t)4 * 4096 * 256 * 2;
  bf16* v_t    = (bf16*)(ws + off); off += (size_t)4 * 256 * 4096 * 2;
  bf16* attn_b = Wqkv_t;
  // x_bf16 (21 MB) aliases q_r (16.8 MB) + head of k_r: x_b dies at GEMM1,
  // q_r/k_r are written only after GEMM1 completes.
  bf16* x_b = q_r;
  if (ws_size < off) return;  // insufficient workspace -> fail loudly

  // fp32 -> bf16 conversions: x elementwise, weights fused into B^T transposes
  k_f2b<<<dim3((4096 * 2560) / (256 * 8)), 256, 0, stream>>>(x, x_b);
  k_transpose_f2b<<<dim3(32, 40), 256, 0, stream>>>(Wq, Wqkv_t, 2048, 2560);
  k_transpose_f2b<<<dim3(16, 40), 256, 0, stream>>>(Wk, Wqkv_t + (size_t)2048 * 2560, 1024, 2560);
  k_transpose_f2b<<<dim3(16, 40), 256, 0, stream>>>(Wv, Wqkv_t + (size_t)3072 * 2560, 1024, 2560);
  k_transpose_f2b<<<dim3(40, 32), 256, 0, stream>>>(Wo, Wo_t, 2560, 2048);
  // fused QKV projection: [4096,2560] x [2560,4096] -> [4096,4096] (bf16 out), 256 blocks
  k_gemm8<bf16><<<dim3(16, 16), 512, 0, stream>>>(x_b, Wqkv_t, qkv_b, 4096, 4096, 2560);
  // RMSNorm + RoPE for q,k (overwrites x_b region -- x_b is dead now)
  k_norm_rope<<<dim3(4096, 12), 64, 0, stream>>>(qkv_b, pos, qw, kw, q_r, k_r);
  // V transpose: qkv_b[t][3072+kh*256+d] -> v_t[kh][d][t]
  k_transpose<<<dim3(4, 64, 4), 256, 0, stream>>>(qkv_b + 3072, v_t, 4096, 4096, 256, (long)256 * 4096);
  // flash attention
  k_attn<<<dim3(64, 8), 256, 0, stream>>>(q_r, k_r, v_t, attn_b);
  // output projection: [4096,2048] x [2048,2560] -> out (FP32 out), 160 blocks
  k_gemm8<float><<<dim3(10, 16), 512, 0, stream>>>(attn_b, Wo_t, out, 4096, 2560, 2048);
}